// Round 9
// baseline (72.376 us; speedup 1.0000x reference)
//
#include <hip/hip_runtime.h>
#include <stdint.h>

// PoolerNeighborMap R27: R26 quadrant engines with the vmcnt races FIXED.
// R26 bug: mixed load+store vmcnt stream counted with K=(NB-1)(L+1) — stores
// retire fast (decrement when data read from VGPRs), so K could be met with
// >(NB-1)L LOADS outstanding -> ch c loads not landed -> stale LDS (steady-
// state race), and the tail kept steady K with <K younger ops (tail race).
// Fix: LOADS-ONLY counting (safe under any store-retirement order, since
// loads retire in-order among loads): steady K=(NB-1)*L; explicit drains
// K=(31-c)*L. Also vmwait<1> added (was missing -> fell to vmcnt(32)).
//   QT<=256: NB=6,L=1: steady 5; drains 4,3,2,1,0
//   QT<=512: NB=3,L=2: steady 4; drains 2,0
//   QT<=768: NB=2,L=3: steady 3; drain 0
// Each of 4 waves owns an output quadrant (5x5 outputs, 2 lanes/output by
// y-sample half, shfl_xor(1) combine), stages its own quarter tile with 16B
// global_load_lds, self-syncs on vmcnt. NO s_barrier in main loop.
// lv3 / qmax>768 blocks: R21 champion path verbatim.

#define NCH 256
#define NPOOL 10
#define POOLF 6144     // LDS pool floats (24KB): 4 engines x 1536
#define CPB 32

typedef float v2f __attribute__((ext_vector_type(2)));

struct BoxInfo {
    float rx1, ry1, rw, rh;
    int   batch, level;
    int   pad0, pad1;
};

// setup + bitonic sort fused: one block, 512 threads.
__global__ __launch_bounds__(512) void prep_kernel(const float* __restrict__ boxes,
                                                   const int* __restrict__ batch_ids,
                                                   int N, BoxInfo* __restrict__ info,
                                                   float* __restrict__ masks_out,
                                                   int* __restrict__ order) {
    __shared__ unsigned keys[512];
    int t = threadIdx.x;
    unsigned key = 0xFFFFFFFFu - (unsigned)(512 - t);
    if (t < N) {
        float x1 = boxes[t * 4 + 0];
        float y1 = boxes[t * 4 + 1];
        float x2 = boxes[t * 4 + 2];
        float y2 = boxes[t * 4 + 3];
        float w = x2 - x1 + 1.0f;
        float h = y2 - y1 + 1.0f;
        float s = sqrtf(w * h);
        int   lv = 0;
        float mk = 0.25f;
        if (s >= 112.0f) { lv = 1; mk = 0.5f; }
        if (s >= 224.0f) { lv = 2; mk = 1.0f; }
        if (s >= 448.0f) { lv = 3; mk = 2.0f; }
        masks_out[t] = mk;

        float cx = x1 + 0.5f * w;
        float cy = y1 + 0.5f * h;
        float ew = w * 1.5f;
        float eh = h * 1.5f;
        float ex1 = cx - 0.5f * ew;
        float ey1 = cy - 0.5f * eh;
        float ex2 = cx + 0.5f * ew - 1.0f;
        float ey2 = cy + 0.5f * eh - 1.0f;

        const float scales[4] = {0.25f, 0.125f, 0.0625f, 0.03125f};
        float sc = scales[lv];
        float rx1 = ex1 * sc, ry1 = ey1 * sc;
        float rx2 = ex2 * sc, ry2 = ey2 * sc;

        BoxInfo bi;
        bi.rx1 = rx1;
        bi.ry1 = ry1;
        bi.rw = fmaxf(rx2 - rx1, 1.0f);
        bi.rh = fmaxf(ry2 - ry1, 1.0f);
        bi.batch = batch_ids[t];
        bi.level = lv;
        bi.pad0 = 0; bi.pad1 = 0;
        info[t] = bi;

        int yc = (int)fminf(fmaxf(0.5f * (y1 + y2), 0.0f), 2047.0f);
        int b = batch_ids[t] & 1;
        key = ((unsigned)lv << 21) | ((unsigned)b << 20) | ((unsigned)yc << 9) | (unsigned)t;
    }
    keys[t] = key;
    __syncthreads();
    for (int k = 2; k <= 512; k <<= 1) {
        for (int j = k >> 1; j > 0; j >>= 1) {
            int ixj = t ^ j;
            if (ixj > t) {
                unsigned a = keys[t], b2 = keys[ixj];
                bool up = ((t & k) == 0);
                if ((a > b2) == up) { keys[t] = b2; keys[ixj] = a; }
            }
            __syncthreads();
        }
    }
    if (t < N) order[t] = (int)(keys[t] & 511u);
}

__device__ __forceinline__ void load_lds16(const float* g, float* l) {
    __builtin_amdgcn_global_load_lds(
        (const __attribute__((address_space(1))) void*)g,
        (__attribute__((address_space(3))) void*)l, 16, 0, 0);
}
__device__ __forceinline__ void load_lds4(const float* g, float* l) {
    __builtin_amdgcn_global_load_lds(
        (const __attribute__((address_space(1))) void*)g,
        (__attribute__((address_space(3))) void*)l, 4, 0, 0);
}

template<int K> __device__ __forceinline__ void vmwait() {
    if constexpr (K == 0)       asm volatile("s_waitcnt vmcnt(0)" ::: "memory");
    else if constexpr (K == 1)  asm volatile("s_waitcnt vmcnt(1)" ::: "memory");
    else if constexpr (K == 2)  asm volatile("s_waitcnt vmcnt(2)" ::: "memory");
    else if constexpr (K == 3)  asm volatile("s_waitcnt vmcnt(3)" ::: "memory");
    else if constexpr (K == 4)  asm volatile("s_waitcnt vmcnt(4)" ::: "memory");
    else if constexpr (K == 5)  asm volatile("s_waitcnt vmcnt(5)" ::: "memory");
    else if constexpr (K == 6)  asm volatile("s_waitcnt vmcnt(6)" ::: "memory");
    else if constexpr (K == 8)  asm volatile("s_waitcnt vmcnt(8)" ::: "memory");
    else if constexpr (K == 16) asm volatile("s_waitcnt vmcnt(16)" ::: "memory");
    else if constexpr (K == 24) asm volatile("s_waitcnt vmcnt(24)" ::: "memory");
    else                        asm volatile("s_waitcnt vmcnt(32)" ::: "memory");
}

#define BARR() do {                                             \
    __builtin_amdgcn_s_barrier();                               \
    __builtin_amdgcn_sched_barrier(0);                          \
} while (0)

__global__ __launch_bounds__(256, 8) void roi_kernel(
        const float* __restrict__ f0, const float* __restrict__ f1,
        const float* __restrict__ f2, const float* __restrict__ f3,
        const BoxInfo* __restrict__ info, const int* __restrict__ order,
        float* __restrict__ out) {
    __shared__ __attribute__((aligned(16))) float ldsp[POOLF];
    __shared__ float4 prm[40];
    __shared__ unsigned bm[7];
    __shared__ int dry[40];
    __shared__ int ylist[40];
    __shared__ int xcol[40];

    int bid = blockIdx.x;
    int n = order[bid >> 3];
    int cblk = (bid & 7) * CPB;
    int t = threadIdx.x;
    int wv = t >> 6;
    int lane = t & 63;

    BoxInfo bi = info[n];
    const float* feat;
    int H, W;
    switch (bi.level) {
        case 0:  feat = f0; H = 200; W = 304; break;
        case 1:  feat = f1; H = 100; W = 152; break;
        case 2:  feat = f2; H = 50;  W = 76;  break;
        default: feat = f3; H = 25;  W = 38;  break;
    }
    int HW = H * W;
    bool lv3 = (bi.level == 3);

    // ---- sample params ----
    if (t < 40) {
        bool isY = t < 20;
        int  s = isY ? t : t - 20;
        float R1 = isY ? bi.ry1 : bi.rx1;
        float RL = isY ? bi.rh  : bi.rw;
        float SZ = isY ? (float)H : (float)W;
        float frac = ((float)s + 0.5f) * 0.05f;
        float cpos = R1 + RL * frac;
        float valid = (cpos > -1.0f && cpos < SZ) ? 1.0f : 0.0f;
        float cc = fmaxf(cpos, 0.0f);
        float cf = floorf(cc);
        int lo = (int)fminf(cf, SZ - 1.0f);
        int hi = min(lo + 1, (int)SZ - 1);
        float fr = (cf >= SZ - 1.0f) ? 0.0f : (cc - cf);
        prm[t] = make_float4(__int_as_float(lo), __int_as_float(hi), fr, valid);
    }
    if (t < 7) bm[t] = 0u;
    __syncthreads();

    // ---- mark distinct y rows (dense); x pair cols ----
    int y_t = 0;
    if (t < 40) {
        float4 yp = prm[t >> 1];
        y_t = (t & 1) ? __float_as_int(yp.y) : __float_as_int(yp.x);
        if (!lv3) atomicOr(&bm[y_t >> 5], 1u << (y_t & 31));
    }
    if (t >= 64 && t < 104) {
        int c2 = t - 64;
        xcol[c2] = min(__float_as_int(prm[20 + (c2 >> 1)].x), W - 2) + (c2 & 1);
    }
    __syncthreads();

    // ---- ranks + row list ----
    if (t < 40) {
        if (lv3) {
            dry[t] = y_t;
        } else {
            int wI = y_t >> 5, bI = y_t & 31;
            int r = 0;
            for (int k = 0; k < 6; ++k)
                if (k < wI) r += __popc(bm[k]);
            r += __popc(bm[wI] & ((bI == 0) ? 0u : ((1u << bI) - 1u)));
            dry[t] = r;
            ylist[r] = y_t;
        }
    }
    __syncthreads();

    // ---- tile geometry (champion) ----
    int Dy   = dry[39] + 1;
    int xm4  = xcol[0] & ~3;
    int span = xcol[39] - xm4 + 1;
    int SPa  = (span + 3) & ~3;
    int SPad = SPa + (((SPa >> 2) & 1) ? 0 : 4);   // odd granule count
    if (lv3) { xm4 = 0; SPad = 38; }
    int T = Dy * SPad;

    // ---- quadrant geometry (block-uniform) ----
    int R0a[2], Dqa[2], C0a[2], SPaa[2], SPqa[2];
#pragma unroll
    for (int hy = 0; hy < 2; ++hy) {
        R0a[hy] = dry[20 * hy];
        Dqa[hy] = dry[20 * hy + 19] - R0a[hy] + 1;
    }
#pragma unroll
    for (int hx = 0; hx < 2; ++hx) {
        int c0 = xcol[20 * hx] & ~3;
        int wd = xcol[20 * hx + 19] - c0 + 1;
        int sa = (wd + 3) & ~3;
        C0a[hx] = c0;
        SPaa[hx] = sa;
        SPqa[hx] = sa + (((sa >> 2) & 1) ? 0 : 4);
    }
    int qmax = 0;
#pragma unroll
    for (int hy = 0; hy < 2; ++hy)
#pragma unroll
        for (int hx = 0; hx < 2; ++hx)
            qmax = max(qmax, Dqa[hy] * SPqa[hx]);
    bool useQ = (!lv3) && (qmax <= 768);

    bool roleC = (wv < 2);
    int wyh = wv >> 1, wxh = wv & 1;

    // ---- per-lane offsets / taps / weights ----
    int vof[8];
    unsigned adr[8];
    float wy[4], wxA[2], wxB[2];
    bool doOut;
    unsigned lbase = (unsigned)(uintptr_t)(__attribute__((address_space(3))) float*)ldsp;
    const float* ub = feat + (size_t)(bi.batch * NCH + cblk) * (size_t)HW;
    size_t HW1 = (size_t)HW;
    float* opq;
    int QT = 0, SPQ = 0;

    if (useQ) {
        int R0 = R0a[wyh], Dq = Dqa[wyh];
        int C0 = C0a[wxh], SPaQ = SPaa[wxh];
        SPQ = SPqa[wxh];
        QT = Dq * SPQ;
        // stage offsets: 16B granules, quarter tile row-major stride SPQ
        {
            int Gq = SPQ >> 2;
            int r  = lane / Gq;
            int gc = lane - r * Gq;
            int qd  = 64 / Gq;
            int rm  = 64 - qd * Gq;
#pragma unroll
            for (int j = 0; j < 3; ++j) {
                int re = min(r, Dq - 1);
                bool pad = (r >= Dq) || ((gc << 2) >= SPaQ);
                vof[j] = ylist[R0 + re] * W + C0 + (pad ? 0 : (gc << 2));
                r += qd; gc += rm;
                if (gc >= Gq) { gc -= Gq; ++r; }
            }
        }
        // compute taps: 2 lanes per output (hq = y-sample half)
        int ooq = min(lane, 49) >> 1;
        int hq  = lane & 1;
        int pyq = 5 * wyh + ooq / 5;
        int pxq = 5 * wxh + (ooq - (ooq / 5) * 5);
        float4 ypq = prm[2 * pyq + hq];
        wy[0] = ypq.w * (1.0f - ypq.z);
        wy[1] = ypq.w * ypq.z;
        int colA0q = 0, colA1q = 0;
#pragma unroll
        for (int ix = 0; ix < 2; ++ix) {
            float4 xp = prm[20 + 2 * pxq + ix];
            int x0 = __float_as_int(xp.x);
            float lx = (x0 >= W - 1) ? 1.0f : xp.z;
            float vx = xp.w * 0.25f;
            if (ix == 0) colA0q = xcol[2 * (2 * pxq)] - C0;
            else         colA1q = xcol[2 * (2 * pxq + 1)] - C0;
            wxA[ix] = vx * (1.0f - lx);
            wxB[ix] = vx * lx;
        }
        int rr0 = dry[4 * pyq + 2 * hq]     - R0;
        int rr1 = dry[4 * pyq + 2 * hq + 1] - R0;
        unsigned qb = lbase + (unsigned)(wv * 6144);   // wv*1536 dwords
        adr[0] = qb + (unsigned)((rr0 * SPQ + colA0q) << 2);
        adr[1] = qb + (unsigned)((rr0 * SPQ + colA1q) << 2);
        adr[2] = qb + (unsigned)((rr1 * SPQ + colA0q) << 2);
        adr[3] = qb + (unsigned)((rr1 * SPQ + colA1q) << 2);
        doOut = (lane < 50) && (hq == 0);
        opq = out + ((size_t)n * NCH + cblk) * (NPOOL * NPOOL) + (pyq * 10 + pxq);
    } else {
        // ---- champion setup (R21) ----
        if (!roleC) {
            if (lv3) {
#pragma unroll
                for (int j = 0; j < 8; ++j)
                    vof[j] = min(j * 128 + (wv - 2) * 64 + lane, HW - 1);
            } else {
                int Gp = SPad >> 2;
                int g0 = (wv - 2) * 64 + lane;
                int r  = g0 / Gp;
                int gc = g0 - r * Gp;
                int q   = 128 / Gp;
                int rem = 128 - q * Gp;
#pragma unroll
                for (int j = 0; j < 6; ++j) {
                    int re = min(r, Dy - 1);
                    bool pad = (r >= Dy) || ((gc << 2) >= SPa);
                    vof[j] = ylist[re] * W + xm4 + (pad ? 0 : (gc << 2));
                    r += q; gc += rem;
                    if (gc >= Gp) { gc -= Gp; ++r; }
                }
            }
        }
        if (roleC) {
            int o = wv * 50 + min(lane, 49);
            int py = o / 10, px = o - py * 10;
            int colA0, colA1;
#pragma unroll
            for (int ix = 0; ix < 2; ++ix) {
                float4 xp = prm[20 + 2 * px + ix];
                int x0 = __float_as_int(xp.x);
                float lx = (x0 >= W - 1) ? 1.0f : xp.z;
                float vx = xp.w * 0.25f;
                if (ix == 0) colA0 = xcol[2 * (2 * px)] - xm4;
                else         colA1 = xcol[2 * (2 * px + 1)] - xm4;
                wxA[ix] = vx * (1.0f - lx);
                wxB[ix] = vx * lx;
            }
#pragma unroll
            for (int iy = 0; iy < 2; ++iy) {
                float4 yp = prm[2 * py + iy];
                int r0 = dry[4 * py + 2 * iy]     * SPad;
                int r1 = dry[4 * py + 2 * iy + 1] * SPad;
                adr[(2 * iy) * 2]     = lbase + (unsigned)((r0 + colA0) << 2);
                adr[(2 * iy) * 2 + 1] = lbase + (unsigned)((r0 + colA1) << 2);
                adr[(2 * iy + 1) * 2]     = lbase + (unsigned)((r1 + colA0) << 2);
                adr[(2 * iy + 1) * 2 + 1] = lbase + (unsigned)((r1 + colA1) << 2);
                wy[2 * iy]     = yp.w * (1.0f - yp.z);
                wy[2 * iy + 1] = yp.w * yp.z;
            }
        }
        doOut = roleC && (lane < 50);
        int o = wv * 50 + min(lane, 49);
        opq = out + ((size_t)n * NCH + cblk) * (NPOOL * NPOOL) + o;
    }

// ---- quadrant engine macros (per-wave, NO barriers) ----
#define STAGEQ(GP, BI, LQ, BQ) do {                                          \
    const float* g_ = (GP);                                                  \
    float* l_ = ldsp + wv * 1536 + (BI) * (BQ);                              \
    _Pragma("unroll")                                                        \
    for (int j = 0; j < (LQ); ++j)                                           \
        load_lds16(g_ + vof[j], l_ + j * 256);                               \
} while (0)

#define COMPQ(BI, BQ, OP) do {                                               \
    unsigned bb_ = (unsigned)((BI) * (BQ) << 2);                             \
    v2f q0, q1, q2, q3;                                                      \
    asm volatile("ds_read2_b32 %0, %1 offset0:0 offset1:1"                   \
                 : "=v"(q0) : "v"(adr[0] + bb_));                            \
    asm volatile("ds_read2_b32 %0, %1 offset0:0 offset1:1"                   \
                 : "=v"(q1) : "v"(adr[1] + bb_));                            \
    asm volatile("ds_read2_b32 %0, %1 offset0:0 offset1:1"                   \
                 : "=v"(q2) : "v"(adr[2] + bb_));                            \
    asm volatile("ds_read2_b32 %0, %1 offset0:0 offset1:1"                   \
                 : "=v"(q3) : "v"(adr[3] + bb_));                            \
    asm volatile("s_waitcnt lgkmcnt(0)" ::: "memory");                       \
    __builtin_amdgcn_sched_barrier(0);                                       \
    float part_ = wy[0] * (wxA[0] * q0.x + wxB[0] * q0.y                     \
                         + wxA[1] * q1.x + wxB[1] * q1.y)                    \
                + wy[1] * (wxA[0] * q2.x + wxB[0] * q2.y                     \
                         + wxA[1] * q3.x + wxB[1] * q3.y);                   \
    float tot_ = part_ + __shfl_xor(part_, 1);                               \
    if (doOut) *(OP) = tot_;                                                 \
} while (0)

// Drain step: vmwait<K=(31-c)*L loads-only> -> COMP(ch c)
#define DRQ(BQ, KV) do {                                                     \
    vmwait<KV>();                                                            \
    COMPQ(cb, BQ, po); po += 100;                                            \
    if (++cb == NBq) cb = 0;                                                 \
} while (0)

// Per-wave pipeline, LOADS-ONLY vmcnt counting (robust to store retirement
// order; loads retire in-order among loads). Steady: after STAGE(ch c+NB-1),
// younger loads than ch c's = (NB-1)*L -> vmwait<(NB-1)*L>. Main loop runs
// c = 0..32-NB (staging always valid); drains follow with K=(31-c)*L.
#define RUNQ(NBq_, LQ, BQ, KW, ...) do {                                     \
    const int NBq = NBq_;                                                    \
    _Pragma("unroll")                                                        \
    for (int b = 0; b < NBq - 1; ++b) STAGEQ(ub + (size_t)b * HW1, b, LQ, BQ); \
    const float* gs = ub + (size_t)(NBq - 1) * HW1;                          \
    float* po = opq;                                                         \
    int sb = NBq - 1, cb = 0;                                                \
    for (int c = 0; c <= 32 - NBq; ++c) {                                    \
        STAGEQ(gs, sb, LQ, BQ);                                              \
        gs += HW1; if (++sb == NBq) sb = 0;                                  \
        vmwait<KW>();                                                        \
        COMPQ(cb, BQ, po); po += 100;                                        \
        if (++cb == NBq) cb = 0;                                             \
    }                                                                        \
    __VA_ARGS__                                                              \
} while (0)

// ---- champion macros (R21, verbatim) ----
#define STAGED2(GP, BI) do {                                                 \
    const float* g_ = (GP);                                                  \
    float* l_ = ldsp + (BI) * 1024 + (wv - 2) * 256;                         \
    load_lds16(g_ + vof[0], l_);                                             \
    load_lds16(g_ + vof[1], l_ + 512);                                       \
} while (0)

#define STAGED3N(GP, BI) do {                                                \
    const float* g_ = (GP);                                                  \
    float* l_ = ldsp + (BI) * 1536 + (wv - 2) * 256;                         \
    load_lds16(g_ + vof[0], l_);                                             \
    load_lds16(g_ + vof[1], l_ + 512);                                       \
    load_lds16(g_ + vof[2], l_ + 1024);                                      \
} while (0)

#define STAGED4(GP, BI) do {                                                 \
    const float* g_ = (GP);                                                  \
    float* l_ = ldsp + (BI) * 2048 + (wv - 2) * 256;                         \
    load_lds16(g_ + vof[0], l_);                                             \
    load_lds16(g_ + vof[1], l_ + 512);                                       \
    load_lds16(g_ + vof[2], l_ + 1024);                                      \
    load_lds16(g_ + vof[3], l_ + 1536);                                      \
} while (0)

#define STAGED6(GP, BI) do {                                                 \
    const float* g_ = (GP);                                                  \
    float* l_ = ldsp + (BI) * 3072 + (wv - 2) * 256;                         \
    load_lds16(g_ + vof[0], l_);                                             \
    load_lds16(g_ + vof[1], l_ + 512);                                       \
    load_lds16(g_ + vof[2], l_ + 1024);                                      \
    load_lds16(g_ + vof[3], l_ + 1536);                                      \
    load_lds16(g_ + vof[4], l_ + 2048);                                      \
    load_lds16(g_ + vof[5], l_ + 2560);                                      \
} while (0)

#define STAGE3(GP, BI) do {                                                  \
    const float* g_ = (GP);                                                  \
    float* l_ = ldsp + (BI) * 1024 + (wv - 2) * 64;                          \
    _Pragma("unroll")                                                        \
    for (int j = 0; j < 8; ++j)                                              \
        load_lds4(g_ + vof[j], l_ + j * 128);                                \
} while (0)

#define COMPX(BUFVv, BI, OP) do {                                            \
    if (roleC) {                                                             \
        unsigned bb_ = (unsigned)((BI) * (BUFVv) << 2);                      \
        v2f q0, q1, q2, q3, q4, q5, q6, q7;                                  \
        asm volatile("ds_read2_b32 %0, %1 offset0:0 offset1:1"               \
                     : "=v"(q0) : "v"(adr[0] + bb_));                        \
        asm volatile("ds_read2_b32 %0, %1 offset0:0 offset1:1"               \
                     : "=v"(q1) : "v"(adr[1] + bb_));                        \
        asm volatile("ds_read2_b32 %0, %1 offset0:0 offset1:1"               \
                     : "=v"(q2) : "v"(adr[2] + bb_));                        \
        asm volatile("ds_read2_b32 %0, %1 offset0:0 offset1:1"               \
                     : "=v"(q3) : "v"(adr[3] + bb_));                        \
        asm volatile("ds_read2_b32 %0, %1 offset0:0 offset1:1"               \
                     : "=v"(q4) : "v"(adr[4] + bb_));                        \
        asm volatile("ds_read2_b32 %0, %1 offset0:0 offset1:1"               \
                     : "=v"(q5) : "v"(adr[5] + bb_));                        \
        asm volatile("ds_read2_b32 %0, %1 offset0:0 offset1:1"               \
                     : "=v"(q6) : "v"(adr[6] + bb_));                        \
        asm volatile("ds_read2_b32 %0, %1 offset0:0 offset1:1"               \
                     : "=v"(q7) : "v"(adr[7] + bb_));                        \
        asm volatile("s_waitcnt lgkmcnt(0)" ::: "memory");                   \
        __builtin_amdgcn_sched_barrier(0);                                   \
        float a_ = wy[0] * (wxA[0] * q0.x + wxB[0] * q0.y                    \
                          + wxA[1] * q1.x + wxB[1] * q1.y)                   \
                 + wy[1] * (wxA[0] * q2.x + wxB[0] * q2.y                    \
                          + wxA[1] * q3.x + wxB[1] * q3.y)                   \
                 + wy[2] * (wxA[0] * q4.x + wxB[0] * q4.y                    \
                          + wxA[1] * q5.x + wxB[1] * q5.y)                   \
                 + wy[3] * (wxA[0] * q6.x + wxB[0] * q6.y                    \
                          + wxA[1] * q7.x + wxB[1] * q7.y);                  \
        if (doOut) *(OP) = a_;                                               \
    }                                                                        \
} while (0)

#define DR1(BUFVv, KV) do {                                                  \
    if (!roleC) vmwait<KV>();                                                \
    BARR();                                                                  \
    COMPX(BUFVv, cb, po); po += 100;                                         \
    if (++cb == NBv) cb = 0;                                                 \
} while (0)

#define RUN1(NBv_, BUFVv, SM, KW, ...) do {                                  \
    const int NBv = NBv_;                                                    \
    if (!roleC) {                                                            \
        _Pragma("unroll")                                                    \
        for (int b = 0; b < NBv - 1; ++b) SM(ub + (size_t)b * HW1, b);       \
    }                                                                        \
    const float* gs = ub + (size_t)(NBv - 1) * HW1;                          \
    float* po = opq;                                                         \
    int sb = NBv - 1, cb = 0;                                                \
    for (int c = 0; c <= 32 - NBv; ++c) {                                    \
        if (!roleC) vmwait<KW>();                                            \
        BARR();                                                              \
        if (!roleC) SM(gs, sb);                                              \
        COMPX(BUFVv, cb, po); po += 100;                                     \
        gs += HW1;                                                           \
        if (++sb == NBv) sb = 0;                                             \
        if (++cb == NBv) cb = 0;                                             \
    }                                                                        \
    __VA_ARGS__                                                              \
} while (0)

#define DRIT(BUFVv, NBv, KSTR) do {                                          \
    if (!roleC) { asm volatile("s_waitcnt vmcnt(" KSTR ")" ::: "memory"); }  \
    BARR(); COMPX(BUFVv, cb, po); po += 100; BARR();                         \
    if (++cb == NBv) cb = 0;                                                 \
} while (0)

#define RUN(NBv, BUFVv, SM, KMAIN, ...) do {                                 \
    if (!roleC) {                                                            \
        _Pragma("unroll")                                                    \
        for (int b = 0; b < NBv - 1; ++b) SM(ub + (size_t)b * HW1, b);       \
    }                                                                        \
    const float* gs = ub + (size_t)(NBv - 1) * HW1;                          \
    float* po = opq;                                                         \
    int sb = NBv - 1, cb = 0;                                                \
    for (int c = 0; c <= 32 - NBv; ++c) {                                    \
        if (!roleC) {                                                        \
            SM(gs, sb);                                                      \
            asm volatile("s_waitcnt vmcnt(" KMAIN ")" ::: "memory");         \
        }                                                                    \
        BARR(); COMPX(BUFVv, cb, po); po += 100; BARR();                     \
        gs += HW1;                                                           \
        if (++sb == NBv) sb = 0;                                             \
        if (++cb == NBv) cb = 0;                                             \
    }                                                                        \
    __VA_ARGS__                                                              \
} while (0)

    if (useQ) {
        // barrier-free per-wave quadrant engines (loads-only vmcnt counts)
        if (QT <= 256) {
            // NB=6, L=1: steady 5; drains (31-c)*1 = 4,3,2,1,0
            RUNQ(6, 1, 256, 5,
                 DRQ(256, 4); DRQ(256, 3); DRQ(256, 2);
                 DRQ(256, 1); DRQ(256, 0););
        } else if (QT <= 512) {
            // NB=3, L=2: steady 4; drains (31-c)*2 = 2,0
            RUNQ(3, 2, 512, 4,
                 DRQ(512, 2); DRQ(512, 0););
        } else {
            // NB=2, L=3: steady 3; drain 0
            RUNQ(2, 3, 768, 3,
                 DRQ(768, 0););
        }
    } else if (lv3) {
        RUN1(6, 1024, STAGE3, 32,
             DR1(1024, 32); DR1(1024, 24); DR1(1024, 16);
             DR1(1024, 8);  DR1(1024, 0););
    } else if (T <= 1024) {
        RUN1(6, 1024, STAGED2, 8,
             DR1(1024, 8); DR1(1024, 4); DR1(1024, 4);
             DR1(1024, 2); DR1(1024, 0););
    } else if (T <= 1536) {
        RUN1(4, 1536, STAGED3N, 6,
             DR1(1536, 6); DR1(1536, 3); DR1(1536, 0););
    } else if (T <= 2048) {
        RUN1(3, 2048, STAGED4, 4,
             DR1(2048, 4); DR1(2048, 0););
    } else {
        RUN(2, 3072, STAGED6, "6",
            DRIT(3072, 2, "0"););
    }

#undef STAGEQ
#undef COMPQ
#undef DRQ
#undef RUNQ
#undef STAGED2
#undef STAGED3N
#undef STAGED4
#undef STAGED6
#undef STAGE3
#undef COMPX
#undef DR1
#undef RUN1
#undef DRIT
#undef RUN
}

extern "C" void kernel_launch(void* const* d_in, const int* in_sizes, int n_in,
                              void* d_out, int out_size, void* d_ws, size_t ws_size,
                              hipStream_t stream) {
    const float* x0 = (const float*)d_in[0];
    const float* x1 = (const float*)d_in[1];
    const float* x2 = (const float*)d_in[2];
    const float* x3 = (const float*)d_in[3];
    const float* boxes = (const float*)d_in[4];
    const int* batch_ids = (const int*)d_in[5];
    int N = in_sizes[4] / 4;

    BoxInfo* info = (BoxInfo*)d_ws;
    int* order = (int*)((char*)d_ws + 512 * sizeof(BoxInfo));
    float* out = (float*)d_out;
    float* masks = out + (size_t)N * NCH * NPOOL * NPOOL;

    prep_kernel<<<1, 512, 0, stream>>>(boxes, batch_ids, N, info, masks, order);

    roi_kernel<<<N * (NCH / CPB), 256, 0, stream>>>(x0, x1, x2, x3, info, order, out);
}

// Round 10
// 60.903 us; speedup vs baseline: 1.1884x; 1.1884x over previous
//
#include <hip/hip_runtime.h>
#include <stdint.h>

// PoolerNeighborMap R28: R21 champion + compute-wave cross-interval tap
// PREFETCH. Champion interval: BARR -> 8x ds_read2 -> lgkm(0) (~160cyc
// stall incl. conflicts) -> FMA. Ch c+1's LDS data is resident one full
// interval before compute reads it, so compute issues ch c+1's reads into
// persistent regs at END of interval c; interval c+1's lgkm(0) finds them
// complete (latency hidden under barrier+stage).
// Safety: (1) WAR: reads@interval c target buf (c+1)%NB, rewritten at
// interval c+2 only after the c+1 barrier that follows compute's lgkm drain.
// (2) stage wait tightened K=(NB-2)L -> K'=(NB-3)L so ch c+1's global loads
// land before interval c's barrier (prefetch-issue point). Needs NB>=4:
//   lv3    : NB=6,L=8: KPRO=32, K'=24; drains 24,16,8,0,0
//   T<=1024: NB=6,L=2: KPRO=8,  K'=6;  drains 6,4,2,0,0
//   T<=1536: NB=4,L=3: KPRO=6,  K'=3;  drains 3,0,0
// (drain K=(30-c)*L = younger-than-ch(c+1) loads; last drain: no prefetch)
// T<=2048 (NB=3: K'=0 would kill stage lookahead) and T>2048 keep champion
// paths verbatim. +16 VGPR persistent taps (40->~56, under 64 cap @(256,8)).

#define NCH 256
#define NPOOL 10
#define POOLF 6144     // LDS pool floats (24KB)
#define CPB 32

typedef float v2f __attribute__((ext_vector_type(2)));

struct BoxInfo {
    float rx1, ry1, rw, rh;
    int   batch, level;
    int   pad0, pad1;
};

// setup + bitonic sort fused: one block, 512 threads.
__global__ __launch_bounds__(512) void prep_kernel(const float* __restrict__ boxes,
                                                   const int* __restrict__ batch_ids,
                                                   int N, BoxInfo* __restrict__ info,
                                                   float* __restrict__ masks_out,
                                                   int* __restrict__ order) {
    __shared__ unsigned keys[512];
    int t = threadIdx.x;
    unsigned key = 0xFFFFFFFFu - (unsigned)(512 - t);
    if (t < N) {
        float x1 = boxes[t * 4 + 0];
        float y1 = boxes[t * 4 + 1];
        float x2 = boxes[t * 4 + 2];
        float y2 = boxes[t * 4 + 3];
        float w = x2 - x1 + 1.0f;
        float h = y2 - y1 + 1.0f;
        float s = sqrtf(w * h);
        int   lv = 0;
        float mk = 0.25f;
        if (s >= 112.0f) { lv = 1; mk = 0.5f; }
        if (s >= 224.0f) { lv = 2; mk = 1.0f; }
        if (s >= 448.0f) { lv = 3; mk = 2.0f; }
        masks_out[t] = mk;

        float cx = x1 + 0.5f * w;
        float cy = y1 + 0.5f * h;
        float ew = w * 1.5f;
        float eh = h * 1.5f;
        float ex1 = cx - 0.5f * ew;
        float ey1 = cy - 0.5f * eh;
        float ex2 = cx + 0.5f * ew - 1.0f;
        float ey2 = cy + 0.5f * eh - 1.0f;

        const float scales[4] = {0.25f, 0.125f, 0.0625f, 0.03125f};
        float sc = scales[lv];
        float rx1 = ex1 * sc, ry1 = ey1 * sc;
        float rx2 = ex2 * sc, ry2 = ey2 * sc;

        BoxInfo bi;
        bi.rx1 = rx1;
        bi.ry1 = ry1;
        bi.rw = fmaxf(rx2 - rx1, 1.0f);
        bi.rh = fmaxf(ry2 - ry1, 1.0f);
        bi.batch = batch_ids[t];
        bi.level = lv;
        bi.pad0 = 0; bi.pad1 = 0;
        info[t] = bi;

        int yc = (int)fminf(fmaxf(0.5f * (y1 + y2), 0.0f), 2047.0f);
        int b = batch_ids[t] & 1;
        key = ((unsigned)lv << 21) | ((unsigned)b << 20) | ((unsigned)yc << 9) | (unsigned)t;
    }
    keys[t] = key;
    __syncthreads();
    for (int k = 2; k <= 512; k <<= 1) {
        for (int j = k >> 1; j > 0; j >>= 1) {
            int ixj = t ^ j;
            if (ixj > t) {
                unsigned a = keys[t], b2 = keys[ixj];
                bool up = ((t & k) == 0);
                if ((a > b2) == up) { keys[t] = b2; keys[ixj] = a; }
            }
            __syncthreads();
        }
    }
    if (t < N) order[t] = (int)(keys[t] & 511u);
}

__device__ __forceinline__ void load_lds16(const float* g, float* l) {
    __builtin_amdgcn_global_load_lds(
        (const __attribute__((address_space(1))) void*)g,
        (__attribute__((address_space(3))) void*)l, 16, 0, 0);
}
__device__ __forceinline__ void load_lds4(const float* g, float* l) {
    __builtin_amdgcn_global_load_lds(
        (const __attribute__((address_space(1))) void*)g,
        (__attribute__((address_space(3))) void*)l, 4, 0, 0);
}

template<int K> __device__ __forceinline__ void vmwait() {
    if constexpr (K == 0)       asm volatile("s_waitcnt vmcnt(0)" ::: "memory");
    else if constexpr (K == 1)  asm volatile("s_waitcnt vmcnt(1)" ::: "memory");
    else if constexpr (K == 2)  asm volatile("s_waitcnt vmcnt(2)" ::: "memory");
    else if constexpr (K == 3)  asm volatile("s_waitcnt vmcnt(3)" ::: "memory");
    else if constexpr (K == 4)  asm volatile("s_waitcnt vmcnt(4)" ::: "memory");
    else if constexpr (K == 6)  asm volatile("s_waitcnt vmcnt(6)" ::: "memory");
    else if constexpr (K == 8)  asm volatile("s_waitcnt vmcnt(8)" ::: "memory");
    else if constexpr (K == 16) asm volatile("s_waitcnt vmcnt(16)" ::: "memory");
    else if constexpr (K == 24) asm volatile("s_waitcnt vmcnt(24)" ::: "memory");
    else                        asm volatile("s_waitcnt vmcnt(32)" ::: "memory");
}

#define BARR() do {                                             \
    __builtin_amdgcn_s_barrier();                               \
    __builtin_amdgcn_sched_barrier(0);                          \
} while (0)

__global__ __launch_bounds__(256, 8) void roi_kernel(
        const float* __restrict__ f0, const float* __restrict__ f1,
        const float* __restrict__ f2, const float* __restrict__ f3,
        const BoxInfo* __restrict__ info, const int* __restrict__ order,
        float* __restrict__ out) {
    __shared__ __attribute__((aligned(16))) float ldsp[POOLF];
    __shared__ float4 prm[40];
    __shared__ unsigned bm[7];
    __shared__ int dry[40];
    __shared__ int ylist[40];
    __shared__ int xcol[40];

    int bid = blockIdx.x;
    int n = order[bid >> 3];
    int cblk = (bid & 7) * CPB;
    int t = threadIdx.x;
    int wv = t >> 6;
    int lane = t & 63;

    BoxInfo bi = info[n];
    const float* feat;
    int H, W;
    switch (bi.level) {
        case 0:  feat = f0; H = 200; W = 304; break;
        case 1:  feat = f1; H = 100; W = 152; break;
        case 2:  feat = f2; H = 50;  W = 76;  break;
        default: feat = f3; H = 25;  W = 38;  break;
    }
    int HW = H * W;
    bool lv3 = (bi.level == 3);

    // ---- sample params ----
    if (t < 40) {
        bool isY = t < 20;
        int  s = isY ? t : t - 20;
        float R1 = isY ? bi.ry1 : bi.rx1;
        float RL = isY ? bi.rh  : bi.rw;
        float SZ = isY ? (float)H : (float)W;
        float frac = ((float)s + 0.5f) * 0.05f;
        float cpos = R1 + RL * frac;
        float valid = (cpos > -1.0f && cpos < SZ) ? 1.0f : 0.0f;
        float cc = fmaxf(cpos, 0.0f);
        float cf = floorf(cc);
        int lo = (int)fminf(cf, SZ - 1.0f);
        int hi = min(lo + 1, (int)SZ - 1);
        float fr = (cf >= SZ - 1.0f) ? 0.0f : (cc - cf);
        prm[t] = make_float4(__int_as_float(lo), __int_as_float(hi), fr, valid);
    }
    if (t < 7) bm[t] = 0u;
    __syncthreads();

    // ---- mark distinct y rows (dense); x pair cols ----
    int y_t = 0;
    if (t < 40) {
        float4 yp = prm[t >> 1];
        y_t = (t & 1) ? __float_as_int(yp.y) : __float_as_int(yp.x);
        if (!lv3) atomicOr(&bm[y_t >> 5], 1u << (y_t & 31));
    }
    if (t >= 64 && t < 104) {
        int c2 = t - 64;
        xcol[c2] = min(__float_as_int(prm[20 + (c2 >> 1)].x), W - 2) + (c2 & 1);
    }
    __syncthreads();

    // ---- ranks + row list ----
    if (t < 40) {
        if (lv3) {
            dry[t] = y_t;
        } else {
            int wI = y_t >> 5, bI = y_t & 31;
            int r = 0;
            for (int k = 0; k < 6; ++k)
                if (k < wI) r += __popc(bm[k]);
            r += __popc(bm[wI] & ((bI == 0) ? 0u : ((1u << bI) - 1u)));
            dry[t] = r;
            ylist[r] = y_t;
        }
    }
    __syncthreads();

    // ---- tile geometry ----
    int Dy   = dry[39] + 1;
    int xm4  = xcol[0] & ~3;
    int span = xcol[39] - xm4 + 1;
    int SPa  = (span + 3) & ~3;
    int SPad = SPa + (((SPa >> 2) & 1) ? 0 : 4);   // odd granule count
    if (lv3) { xm4 = 0; SPad = 38; }
    int T = Dy * SPad;

    bool roleC = (wv < 2);

    // ---- stage-wave per-lane source offsets ----
    int vof[8];
    if (!roleC) {
        if (lv3) {
#pragma unroll
            for (int j = 0; j < 8; ++j)
                vof[j] = min(j * 128 + (wv - 2) * 64 + lane, HW - 1);
        } else {
            int Gp = SPad >> 2;
            int g0 = (wv - 2) * 64 + lane;
            int r  = g0 / Gp;
            int gc = g0 - r * Gp;
            int q   = 128 / Gp;
            int rem = 128 - q * Gp;
#pragma unroll
            for (int j = 0; j < 6; ++j) {
                int re = min(r, Dy - 1);
                bool pad = (r >= Dy) || ((gc << 2) >= SPa);
                vof[j] = ylist[re] * W + xm4 + (pad ? 0 : (gc << 2));
                r += q; gc += rem;
                if (gc >= Gp) { gc -= Gp; ++r; }
            }
        }
    }

    // ---- compute-wave taps: 8 byte-addresses (4 rows x 2 x-pairs) + weights ----
    bool doOut = roleC && (lane < 50);
    float wy[4];
    float wxA[2], wxB[2];
    unsigned adr[8];
    unsigned lbase = (unsigned)(uintptr_t)(__attribute__((address_space(3))) float*)ldsp;
    if (roleC) {
        int o = wv * 50 + min(lane, 49);
        int py = o / 10, px = o - py * 10;
        int colA0, colA1;
#pragma unroll
        for (int ix = 0; ix < 2; ++ix) {
            float4 xp = prm[20 + 2 * px + ix];
            int x0 = __float_as_int(xp.x);
            float lx = (x0 >= W - 1) ? 1.0f : xp.z;
            float vx = xp.w * 0.25f;
            if (ix == 0) colA0 = xcol[2 * (2 * px)] - xm4;
            else         colA1 = xcol[2 * (2 * px + 1)] - xm4;
            wxA[ix] = vx * (1.0f - lx);
            wxB[ix] = vx * lx;
        }
#pragma unroll
        for (int iy = 0; iy < 2; ++iy) {
            float4 yp = prm[2 * py + iy];
            int r0 = dry[4 * py + 2 * iy]     * SPad;
            int r1 = dry[4 * py + 2 * iy + 1] * SPad;
            adr[(2 * iy) * 2]     = lbase + (unsigned)((r0 + colA0) << 2);
            adr[(2 * iy) * 2 + 1] = lbase + (unsigned)((r0 + colA1) << 2);
            adr[(2 * iy + 1) * 2]     = lbase + (unsigned)((r1 + colA0) << 2);
            adr[(2 * iy + 1) * 2 + 1] = lbase + (unsigned)((r1 + colA1) << 2);
            wy[2 * iy]     = yp.w * (1.0f - yp.z);
            wy[2 * iy + 1] = yp.w * yp.z;
        }
    }

    const float* ub = feat + (size_t)(bi.batch * NCH + cblk) * (size_t)HW;
    size_t HW1 = (size_t)HW;
    float* op;
    {
        int o = wv * 50 + min(lane, 49);
        op = out + ((size_t)n * NCH + cblk) * (NPOOL * NPOOL) + o;
    }

#define STAGED2(GP, BI) do {                                                 \
    const float* g_ = (GP);                                                  \
    float* l_ = ldsp + (BI) * 1024 + (wv - 2) * 256;                         \
    load_lds16(g_ + vof[0], l_);                                             \
    load_lds16(g_ + vof[1], l_ + 512);                                       \
} while (0)

#define STAGED3N(GP, BI) do {                                                \
    const float* g_ = (GP);                                                  \
    float* l_ = ldsp + (BI) * 1536 + (wv - 2) * 256;                         \
    load_lds16(g_ + vof[0], l_);                                             \
    load_lds16(g_ + vof[1], l_ + 512);                                       \
    load_lds16(g_ + vof[2], l_ + 1024);                                      \
} while (0)

#define STAGED4(GP, BI) do {                                                 \
    const float* g_ = (GP);                                                  \
    float* l_ = ldsp + (BI) * 2048 + (wv - 2) * 256;                         \
    load_lds16(g_ + vof[0], l_);                                             \
    load_lds16(g_ + vof[1], l_ + 512);                                       \
    load_lds16(g_ + vof[2], l_ + 1024);                                      \
    load_lds16(g_ + vof[3], l_ + 1536);                                      \
} while (0)

#define STAGED6(GP, BI) do {                                                 \
    const float* g_ = (GP);                                                  \
    float* l_ = ldsp + (BI) * 3072 + (wv - 2) * 256;                         \
    load_lds16(g_ + vof[0], l_);                                             \
    load_lds16(g_ + vof[1], l_ + 512);                                       \
    load_lds16(g_ + vof[2], l_ + 1024);                                      \
    load_lds16(g_ + vof[3], l_ + 1536);                                      \
    load_lds16(g_ + vof[4], l_ + 2048);                                      \
    load_lds16(g_ + vof[5], l_ + 2560);                                      \
} while (0)

#define STAGE3(GP, BI) do {                                                  \
    const float* g_ = (GP);                                                  \
    float* l_ = ldsp + (BI) * 1024 + (wv - 2) * 64;                          \
    _Pragma("unroll")                                                        \
    for (int j = 0; j < 8; ++j)                                              \
        load_lds4(g_ + vof[j], l_ + j * 128);                                \
} while (0)

// ---- prefetch primitives: issue ch reads into persistent p0..p7 ----
#define ISSUE8(BUFVv, BI) do {                                               \
    unsigned bb_ = (unsigned)((BI) * (BUFVv) << 2);                          \
    asm volatile("ds_read2_b32 %0, %1 offset0:0 offset1:1"                   \
                 : "=v"(p0) : "v"(adr[0] + bb_));                            \
    asm volatile("ds_read2_b32 %0, %1 offset0:0 offset1:1"                   \
                 : "=v"(p1) : "v"(adr[1] + bb_));                            \
    asm volatile("ds_read2_b32 %0, %1 offset0:0 offset1:1"                   \
                 : "=v"(p2) : "v"(adr[2] + bb_));                            \
    asm volatile("ds_read2_b32 %0, %1 offset0:0 offset1:1"                   \
                 : "=v"(p3) : "v"(adr[3] + bb_));                            \
    asm volatile("ds_read2_b32 %0, %1 offset0:0 offset1:1"                   \
                 : "=v"(p4) : "v"(adr[4] + bb_));                            \
    asm volatile("ds_read2_b32 %0, %1 offset0:0 offset1:1"                   \
                 : "=v"(p5) : "v"(adr[5] + bb_));                            \
    asm volatile("ds_read2_b32 %0, %1 offset0:0 offset1:1"                   \
                 : "=v"(p6) : "v"(adr[6] + bb_));                            \
    asm volatile("ds_read2_b32 %0, %1 offset0:0 offset1:1"                   \
                 : "=v"(p7) : "v"(adr[7] + bb_));                            \
} while (0)

// consume p0..p7 (reads issued previous interval; latency hidden)
#define FMAOUT(OP) do {                                                      \
    asm volatile("s_waitcnt lgkmcnt(0)" ::: "memory");                       \
    __builtin_amdgcn_sched_barrier(0);                                       \
    float a_ = wy[0] * (wxA[0] * p0.x + wxB[0] * p0.y                        \
                      + wxA[1] * p1.x + wxB[1] * p1.y)                       \
             + wy[1] * (wxA[0] * p2.x + wxB[0] * p2.y                        \
                      + wxA[1] * p3.x + wxB[1] * p3.y)                       \
             + wy[2] * (wxA[0] * p4.x + wxB[0] * p4.y                        \
                      + wxA[1] * p5.x + wxB[1] * p5.y)                       \
             + wy[3] * (wxA[0] * p6.x + wxB[0] * p6.y                       \
                      + wxA[1] * p7.x + wxB[1] * p7.y);                      \
    if (doOut) *(OP) = a_;                                                   \
} while (0)

// drain with prefetch: vmwait<K=(30-c)*L> -> BARR -> FMA(ch c) [-> issue c+1]
#define DR1PF(BUFVv, KV, DOISS) do {                                         \
    if (!roleC) vmwait<KV>();                                                \
    BARR();                                                                  \
    if (roleC) { FMAOUT(po); if (DOISS) ISSUE8(BUFVv, cbn); }                \
    po += 100;                                                               \
    if (++cbn == NBv) cbn = 0;                                               \
} while (0)

// prefetch main loop: prologue stages 0..NB-2, vmwait<KPRO=(NB-2)L> (ch0
// landed), BARR, issue ch0 reads. Interval c: vmwait<KP=(NB-3)L> (ch c+1
// landed) -> BARR -> STAGE(ch c+NB-1) || FMA(ch c) + issue reads(ch c+1).
#define RUN1PF(NBv_, BUFVv, SM, KPRO, KP, ...) do {                          \
    const int NBv = NBv_;                                                    \
    if (!roleC) {                                                            \
        _Pragma("unroll")                                                    \
        for (int b = 0; b < NBv - 1; ++b) SM(ub + (size_t)b * HW1, b);       \
        vmwait<KPRO>();                                                      \
    }                                                                        \
    BARR();                                                                  \
    if (roleC) ISSUE8(BUFVv, 0);                                             \
    const float* gs = ub + (size_t)(NBv - 1) * HW1;                          \
    float* po = op;                                                          \
    int sb = NBv - 1, cbn = 1;                                               \
    for (int c = 0; c <= 32 - NBv; ++c) {                                    \
        if (!roleC) vmwait<KP>();                                            \
        BARR();                                                              \
        if (!roleC) SM(gs, sb);                                              \
        if (roleC) { FMAOUT(po); ISSUE8(BUFVv, cbn); }                       \
        po += 100;                                                           \
        gs += HW1;                                                           \
        if (++sb == NBv) sb = 0;                                             \
        if (++cbn == NBv) cbn = 0;                                           \
    }                                                                        \
    __VA_ARGS__                                                              \
} while (0)

// ---- champion non-prefetch forms (R21, verbatim) ----
#define COMPX(BUFVv, BI, OP) do {                                            \
    if (roleC) {                                                             \
        unsigned bb_ = (unsigned)((BI) * (BUFVv) << 2);                      \
        v2f q0, q1, q2, q3, q4, q5, q6, q7;                                  \
        asm volatile("ds_read2_b32 %0, %1 offset0:0 offset1:1"               \
                     : "=v"(q0) : "v"(adr[0] + bb_));                        \
        asm volatile("ds_read2_b32 %0, %1 offset0:0 offset1:1"               \
                     : "=v"(q1) : "v"(adr[1] + bb_));                        \
        asm volatile("ds_read2_b32 %0, %1 offset0:0 offset1:1"               \
                     : "=v"(q2) : "v"(adr[2] + bb_));                        \
        asm volatile("ds_read2_b32 %0, %1 offset0:0 offset1:1"               \
                     : "=v"(q3) : "v"(adr[3] + bb_));                        \
        asm volatile("ds_read2_b32 %0, %1 offset0:0 offset1:1"               \
                     : "=v"(q4) : "v"(adr[4] + bb_));                        \
        asm volatile("ds_read2_b32 %0, %1 offset0:0 offset1:1"               \
                     : "=v"(q5) : "v"(adr[5] + bb_));                        \
        asm volatile("ds_read2_b32 %0, %1 offset0:0 offset1:1"               \
                     : "=v"(q6) : "v"(adr[6] + bb_));                        \
        asm volatile("ds_read2_b32 %0, %1 offset0:0 offset1:1"               \
                     : "=v"(q7) : "v"(adr[7] + bb_));                        \
        asm volatile("s_waitcnt lgkmcnt(0)" ::: "memory");                   \
        __builtin_amdgcn_sched_barrier(0);                                   \
        float a_ = wy[0] * (wxA[0] * q0.x + wxB[0] * q0.y                    \
                          + wxA[1] * q1.x + wxB[1] * q1.y)                   \
                 + wy[1] * (wxA[0] * q2.x + wxB[0] * q2.y                    \
                          + wxA[1] * q3.x + wxB[1] * q3.y)                   \
                 + wy[2] * (wxA[0] * q4.x + wxB[0] * q4.y                    \
                          + wxA[1] * q5.x + wxB[1] * q5.y)                   \
                 + wy[3] * (wxA[0] * q6.x + wxB[0] * q6.y                    \
                          + wxA[1] * q7.x + wxB[1] * q7.y);                  \
        if (doOut) *(OP) = a_;                                               \
    }                                                                        \
} while (0)

#define DR1(BUFVv, KV) do {                                                  \
    if (!roleC) vmwait<KV>();                                                \
    BARR();                                                                  \
    COMPX(BUFVv, cb, po); po += 100;                                         \
    if (++cb == NBv) cb = 0;                                                 \
} while (0)

#define RUN1(NBv_, BUFVv, SM, KW, ...) do {                                  \
    const int NBv = NBv_;                                                    \
    if (!roleC) {                                                            \
        _Pragma("unroll")                                                    \
        for (int b = 0; b < NBv - 1; ++b) SM(ub + (size_t)b * HW1, b);       \
    }                                                                        \
    const float* gs = ub + (size_t)(NBv - 1) * HW1;                          \
    float* po = op;                                                          \
    int sb = NBv - 1, cb = 0;                                                \
    for (int c = 0; c <= 32 - NBv; ++c) {                                    \
        if (!roleC) vmwait<KW>();                                            \
        BARR();                                                              \
        if (!roleC) SM(gs, sb);                                              \
        COMPX(BUFVv, cb, po); po += 100;                                     \
        gs += HW1;                                                           \
        if (++sb == NBv) sb = 0;                                             \
        if (++cb == NBv) cb = 0;                                             \
    }                                                                        \
    __VA_ARGS__                                                              \
} while (0)

#define DRIT(BUFVv, NBv, KSTR) do {                                          \
    if (!roleC) { asm volatile("s_waitcnt vmcnt(" KSTR ")" ::: "memory"); }  \
    BARR(); COMPX(BUFVv, cb, po); po += 100; BARR();                         \
    if (++cb == NBv) cb = 0;                                                 \
} while (0)

#define RUN(NBv, BUFVv, SM, KMAIN, ...) do {                                 \
    if (!roleC) {                                                            \
        _Pragma("unroll")                                                    \
        for (int b = 0; b < NBv - 1; ++b) SM(ub + (size_t)b * HW1, b);       \
    }                                                                        \
    const float* gs = ub + (size_t)(NBv - 1) * HW1;                          \
    float* po = op;                                                          \
    int sb = NBv - 1, cb = 0;                                                \
    for (int c = 0; c <= 32 - NBv; ++c) {                                    \
        if (!roleC) {                                                        \
            SM(gs, sb);                                                      \
            asm volatile("s_waitcnt vmcnt(" KMAIN ")" ::: "memory");         \
        }                                                                    \
        BARR(); COMPX(BUFVv, cb, po); po += 100; BARR();                     \
        gs += HW1;                                                           \
        if (++sb == NBv) sb = 0;                                             \
        if (++cb == NBv) cb = 0;                                             \
    }                                                                        \
    __VA_ARGS__                                                              \
} while (0)

    v2f p0, p1, p2, p3, p4, p5, p6, p7;   // persistent prefetch taps

    if (lv3) {
        // NB=6, L=8: KPRO=32, K'=24; drains (30-c)*8 = 24,16,8,0; last 0
        RUN1PF(6, 1024, STAGE3, 32, 24,
               DR1PF(1024, 24, 1); DR1PF(1024, 16, 1); DR1PF(1024, 8, 1);
               DR1PF(1024, 0, 1);  DR1PF(1024, 0, 0););
    } else if (T <= 1024) {
        // NB=6, L=2: KPRO=8, K'=6; drains 6,4,2,0; last 0
        RUN1PF(6, 1024, STAGED2, 8, 6,
               DR1PF(1024, 6, 1); DR1PF(1024, 4, 1); DR1PF(1024, 2, 1);
               DR1PF(1024, 0, 1); DR1PF(1024, 0, 0););
    } else if (T <= 1536) {
        // NB=4, L=3: KPRO=6, K'=3; drains 3,0; last 0
        RUN1PF(4, 1536, STAGED3N, 6, 3,
               DR1PF(1536, 3, 1); DR1PF(1536, 0, 1); DR1PF(1536, 0, 0););
    } else if (T <= 2048) {
        // champion NB=3 (K'=0 would kill stage lookahead -> no prefetch)
        RUN1(3, 2048, STAGED4, 4,
             DR1(2048, 4); DR1(2048, 0););
    } else {
        RUN(2, 3072, STAGED6, "6",
            DRIT(3072, 2, "0"););
    }

#undef STAGED2
#undef STAGED3N
#undef STAGED4
#undef STAGED6
#undef STAGE3
#undef ISSUE8
#undef FMAOUT
#undef DR1PF
#undef RUN1PF
#undef COMPX
#undef DR1
#undef RUN1
#undef DRIT
#undef RUN
}

extern "C" void kernel_launch(void* const* d_in, const int* in_sizes, int n_in,
                              void* d_out, int out_size, void* d_ws, size_t ws_size,
                              hipStream_t stream) {
    const float* x0 = (const float*)d_in[0];
    const float* x1 = (const float*)d_in[1];
    const float* x2 = (const float*)d_in[2];
    const float* x3 = (const float*)d_in[3];
    const float* boxes = (const float*)d_in[4];
    const int* batch_ids = (const int*)d_in[5];
    int N = in_sizes[4] / 4;

    BoxInfo* info = (BoxInfo*)d_ws;
    int* order = (int*)((char*)d_ws + 512 * sizeof(BoxInfo));
    float* out = (float*)d_out;
    float* masks = out + (size_t)N * NCH * NPOOL * NPOOL;

    prep_kernel<<<1, 512, 0, stream>>>(boxes, batch_ids, N, info, masks, order);

    roi_kernel<<<N * (NCH / CPB), 256, 0, stream>>>(x0, x1, x2, x3, info, order, out);
}